// Round 16
// baseline (9434.343 us; speedup 1.0000x reference)
//
#include <hip/hip_runtime.h>

namespace {
constexpr int B = 128;      // batch
constexpr int D = 80;       // mel dim
constexpr int H = 256;      // hidden
constexpr int PP = 128;     // prenet out
constexpr int TIN = 512;    // encoder steps
constexpr int RSTEPS = 200; // reduced steps
constexpr int RF = 5;       // reduction factor
constexpr int HB = H * B;   // ring slot stride
}

__device__ __forceinline__ float sigm(float x) { return 1.f / (1.f + __expf(-x)); }
__device__ __forceinline__ float tanh_(float x) { return 1.f - 2.f / (__expf(2.f * x) + 1.f); }
__device__ __forceinline__ unsigned short f2bf(float f) {  // RNE
  unsigned int u = __float_as_uint(f);
  u += 0x7fffu + ((u >> 16) & 1u);
  return (unsigned short)(u >> 16);
}
__device__ __forceinline__ void bf2x(unsigned int w, float& f0, float& f1) {
  f0 = __uint_as_float(w << 16);
  f1 = __uint_as_float(w & 0xffff0000u);
}
__device__ __forceinline__ void unpack8(uint4 w, float* f) {
  bf2x(w.x, f[0], f[1]); bf2x(w.y, f[2], f[3]);
  bf2x(w.z, f[4], f[5]); bf2x(w.w, f[6], f[7]);
}
__device__ __forceinline__ float dot8(uint4 w, float4 x0, float4 x1) {
  float f0, f1, a;
  bf2x(w.x, f0, f1); a  = f0 * x0.x + f1 * x0.y;
  bf2x(w.y, f0, f1); a += f0 * x0.z + f1 * x0.w;
  bf2x(w.z, f0, f1); a += f0 * x1.x + f1 * x1.y;
  bf2x(w.w, f0, f1); a += f0 * x1.z + f1 * x1.w;
  return a;
}

// ---------------------------------------------------------------------------
// R13-proven layout: contiguous 32-row reads, scattered bf16 stores.
__global__ __launch_bounds__(256) void k_keys(const float* __restrict__ mem,
                                              const float* __restrict__ Wm,
                                              unsigned short* __restrict__ keysB) {
  const int k = threadIdx.x;
  const int m0 = blockIdx.x * 32;
  const float* xb = mem + (size_t)m0 * H;
  float acc[32];
#pragma unroll
  for (int i = 0; i < 32; ++i) acc[i] = 0.f;
  for (int h = 0; h < H; h += 4) {
    const float w0 = Wm[(h + 0) * H + k];
    const float w1 = Wm[(h + 1) * H + k];
    const float w2 = Wm[(h + 2) * H + k];
    const float w3 = Wm[(h + 3) * H + k];
#pragma unroll
    for (int mi = 0; mi < 32; ++mi) {
      const float4 x = *reinterpret_cast<const float4*>(xb + (size_t)mi * H + h);
      acc[mi] += x.x * w0 + x.y * w1 + x.z * w2 + x.w * w3;
    }
  }
#pragma unroll
  for (int mi = 0; mi < 32; ++mi) {
    const int m = m0 + mi, t = m >> 7, bb = m & 127;
    keysB[((size_t)bb * TIN + t) * H + k] = f2bf(acc[mi]);
  }
}

__global__ __launch_bounds__(256) void k_memB(const float* __restrict__ mem,
                                              unsigned short* __restrict__ memB) {
  const int m = blockIdx.x, t = m >> 7, bb = m & 127;
  memB[((size_t)bb * TIN + t) * H + threadIdx.x] = f2bf(mem[(size_t)m * H + threadIdx.x]);
}

__global__ __launch_bounds__(256) void k_packWq(const float* __restrict__ W,
                                                unsigned short* __restrict__ Wp) {
  const int idx = blockIdx.x * 256 + threadIdx.x;
  const int k = idx >> 8, c = idx & 255;
  Wp[(((size_t)(k >> 3) * 256) + c) * 8 + (k & 7)] = f2bf(W[idx]);
}

// pack GRU weight W[K][768] (cols z|r|c) -> row-interleaved bf16:
// dst[(rowOff+k)*1024 + (j>>1)*8 + (j&1)*4 + g]; slots 3,7 pad.
__global__ __launch_bounds__(256) void k_packG(const float* __restrict__ W,
                                               unsigned short* __restrict__ dst,
                                               int K, int rowOff) {
  const int idx = blockIdx.x * 256 + threadIdx.x;
  if (idx >= K * 768) return;
  const int k = idx / 768, c = idx - k * 768;
  const int g = c >> 8, j = c & 255;
  dst[((size_t)(rowOff + k) * 128 + (j >> 1)) * 8 + (j & 1) * 4 + g] = f2bf(W[idx]);
}

// Hoisted prenet -> preT[t][j][b] fp32
__global__ __launch_bounds__(256) void k_prenet(
    const float* __restrict__ outs, const float* __restrict__ Wp0,
    const float* __restrict__ bp0, const float* __restrict__ Wp1,
    const float* __restrict__ bp1, float* __restrict__ preT) {
  const int t = blockIdx.x >> 7, b = blockIdx.x & 127, tid = threadIdx.x;
  __shared__ float f[80];
  __shared__ float p0[256];
  __shared__ float s2[256];
  if (tid < 80)
    f[tid] = (t == 0) ? 0.f
                      : __builtin_nontemporal_load(
                            &outs[((size_t)(t * RF - 1) * B + b) * D + tid]);
  __syncthreads();
  {
    float a = bp0[tid];
#pragma unroll 8
    for (int k = 0; k < 80; ++k) a += f[k] * Wp0[k * 256 + tid];
    p0[tid] = fmaxf(a, 0.f);
  }
  __syncthreads();
  {
    const int c = tid & 127, kh = tid >> 7;
    float a = 0.f;
#pragma unroll 8
    for (int k = kh * 128; k < kh * 128 + 128; ++k) a += p0[k] * Wp1[k * 128 + c];
    s2[kh * 128 + c] = a;
  }
  __syncthreads();
  if (tid < 128)
    preT[((size_t)t * PP + tid) * B + b] = fmaxf(bp1[tid] + s2[tid] + s2[128 + tid], 0.f);
}

// ---------------------------------------------------------------------------
// 8-wave GRU body, NJP j-pairs per block. rel -> (grp = rel>>1, bh = rel&1).
// If pctx0 != nullptr, x2 reconstructed from 2 attention partials via msp.
template <int NJP>
__device__ void gru_body(const unsigned short* __restrict__ wp, int K1, int K2,
                         int KH, const float* __restrict__ xT1,
                         const float* __restrict__ xT2,
                         const float* __restrict__ pctx0,
                         const float* __restrict__ msp,
                         const float* __restrict__ hT_old,
                         const float* __restrict__ b3, float* __restrict__ hT_new,
                         const float* __restrict__ resInT,
                         float* __restrict__ resOutT, int rel, float* smem) {
  const int tid = threadIdx.x;
  float* part = smem;                       // 8 * NJP*512
  float* red = smem + 8 * NJP * 512;        // NJP*512
  const int grp = rel >> 1, bh = rel & 1;
  const int lane = tid & 63, wv = tid >> 6;
  const int b = bh * 64 + lane;

  float c0 = 0.f, c1 = 0.f;
  if (pctx0) {
    const float m0 = msp[b], s0 = msp[B + b];
    const float m1 = msp[2 * B + b], s1 = msp[3 * B + b];
    const float M = fmaxf(m0, m1);
    const float e0 = __expf(m0 - M), e1 = __expf(m1 - M);
    const float inv = 1.f / (s0 * e0 + s1 * e1);
    c0 = e0 * inv; c1 = e1 * inv;
  }

  const uint4* wp4 = reinterpret_cast<const uint4*>(wp);
  const int K12 = K1 + K2, KT = K12 + KH;
  const int KS = KT >> 3;
  const int k0 = wv * KS, k1 = k0 + KS;

  float acc[NJP * 8];
#pragma unroll
  for (int i = 0; i < NJP * 8; ++i) acc[i] = 0.f;
  float f0, f1;

#define UPD(wq, xv, base, CS)                                                  \
  bf2x(wq.x, f0, f1); acc[base + 0] += f0 * xv; acc[base + 1] += f1 * xv;      \
  bf2x(wq.y, f0, f1); acc[base + CS] += f0 * xv;                               \
  bf2x(wq.z, f0, f1); acc[base + 4] += f0 * xv; acc[base + 5] += f1 * xv;      \
  bf2x(wq.w, f0, f1); acc[base + 4 + CS] += f0 * xv;

  const int e1i = (k1 < K1) ? k1 : K1;
#pragma unroll 2
  for (int k = k0; k < e1i; ++k) {
    const float x = xT1[k * B + b];
#pragma unroll
    for (int p = 0; p < NJP; ++p) {
      const uint4 w = wp4[(size_t)k * 128 + grp * NJP + p];
      UPD(w, x, p * 8, 2)
    }
  }
  const int s2i = (k0 > K1) ? k0 : K1, e2i = (k1 < K12) ? k1 : K12;
#pragma unroll 2
  for (int k = s2i; k < e2i; ++k) {
    const int kk = k - K1;
    const float x = pctx0 ? (c0 * pctx0[kk * B + b] + c1 * pctx0[(256 + kk) * B + b])
                          : xT2[kk * B + b];
#pragma unroll
    for (int p = 0; p < NJP; ++p) {
      const uint4 w = wp4[(size_t)k * 128 + grp * NJP + p];
      UPD(w, x, p * 8, 2)
    }
  }
  const int s3i = (k0 > K12) ? k0 : K12;
#pragma unroll 2
  for (int k = s3i; k < k1; ++k) {
    const float x = hT_old[(k - K12) * B + b];
#pragma unroll
    for (int p = 0; p < NJP; ++p) {
      const uint4 w = wp4[(size_t)k * 128 + grp * NJP + p];
      UPD(w, x, p * 8, 3)
    }
  }
#undef UPD

  float* pw = part + wv * (NJP * 512);
#pragma unroll
  for (int i = 0; i < NJP * 8; ++i) pw[i * 64 + lane] = acc[i];
  __syncthreads();
  for (int idx = tid; idx < NJP * 512; idx += 512) {
    float s = 0.f;
#pragma unroll
    for (int w = 0; w < 8; ++w) s += part[w * (NJP * 512) + idx];
    red[idx] = s;
  }
  __syncthreads();
  if (tid < NJP * 128) {
    const int jl = tid >> 6, ln = tid & 63;
    const int j = grp * (NJP * 2) + jl;
    const int bb = bh * 64 + ln;
    const float az = red[(jl * 4 + 0) * 64 + ln];
    const float ar = red[(jl * 4 + 1) * 64 + ln];
    const float acx = red[(jl * 4 + 2) * 64 + ln];
    const float ach = red[(jl * 4 + 3) * 64 + ln];
    const float z = sigm(az + b3[j]);
    const float r = sigm(ar + b3[H + j]);
    const float c = tanh_(acx + r * ach + b3[2 * H + j]);
    const float hold = hT_old[j * B + bb];
    const float hn = (1.f - z) * hold + z * c;
    hT_new[j * B + bb] = hn;
    if (resOutT) resOutT[j * B + bb] = resInT[j * B + bb] + hn;
  }
}

// qW stage (512 threads, one block per b): qkT[c][b] = sum_k q[k][b] Wq[k][c]
__device__ void qw_body(int b, const float* __restrict__ qT,
                        const unsigned short* __restrict__ wqB,
                        float* __restrict__ qkT, float* smem) {
  const int tid = threadIdx.x;
  float* hA = smem;              // 256
  float* scr = smem + 256;       // 512
  if (tid < 256) hA[tid] = qT[tid * B + b];
  __syncthreads();
  const float4* hA4 = reinterpret_cast<const float4*>(hA);
  const uint4* wQ = reinterpret_cast<const uint4*>(wqB);
  const int c = tid & 255, ks = tid >> 8;
  float a = 0.f;
#pragma unroll
  for (int q = 0; q < 16; ++q) {
    const int kg = ks * 16 + q;
    a += dot8(wQ[(size_t)kg * 256 + c], hA4[kg * 2], hA4[kg * 2 + 1]);
  }
  scr[ks * 256 + c] = a;
  __syncthreads();
  if (tid < 256) qkT[tid * B + b] = scr[tid] + scr[256 + tid];
}

// dense (512 threads) + alpha finalize for step s, batch row b
__device__ void dense_body(int s, int b, const float* __restrict__ res1T,
                           const float* __restrict__ Wo,
                           const float* __restrict__ bo, float* __restrict__ dout,
                           const float* __restrict__ pvalsS,
                           const float* __restrict__ msS,
                           float* __restrict__ alpha, float* smem) {
  const int tid = threadIdx.x;
  float* red = smem;             // 256
  float* part = smem + 256;      // 512
  if (tid < 256) red[tid] = res1T[tid * B + b];
  __syncthreads();
  {
    const int ks = tid >> 7, c = tid & 127;
    float a = 0.f;
    if (c < D) {
#pragma unroll 8
      for (int k = ks * 64; k < ks * 64 + 64; ++k) a += red[k] * Wo[k * D + c];
    }
    part[ks * 128 + c] = a;
  }
  __syncthreads();
  if (tid < D) {
    float dv = bo[tid];
#pragma unroll
    for (int ks = 0; ks < 4; ++ks) dv += part[ks * 128 + tid];
    const size_t base = (size_t)s * RF * (B * D) + (size_t)b * D + tid;
#pragma unroll
    for (int i = 0; i < RF; ++i)
      __builtin_nontemporal_store(dv, &dout[base + (size_t)i * (B * D)]);
  }
  const float m0 = msS[b], s0 = msS[B + b], m1 = msS[2 * B + b], s1 = msS[3 * B + b];
  const float M = fmaxf(m0, m1);
  const float f0 = __expf(m0 - M), f1 = __expf(m1 - M);
  const float inv = 1.f / (s0 * f0 + s1 * f1);
  const float cc = (tid < 256) ? f0 * inv : f1 * inv;
  __builtin_nontemporal_store(pvalsS[(size_t)b * TIN + tid] * cc,
                              &alpha[((size_t)s * B + b) * TIN + tid]);
}

// attention half (512 threads): e over 256 t's (qk precomputed) + partial
// softmax + pctx
__device__ void attn_half_body(int b, int half, const float* __restrict__ qkT,
                               const float* __restrict__ v_att,
                               const unsigned short* __restrict__ keysB,
                               const unsigned short* __restrict__ memB,
                               float* __restrict__ pvalsS, float* __restrict__ pctxS,
                               float* __restrict__ msS, float* smem) {
  const int tid = threadIdx.x;
  const int lane = tid & 63, wv = tid >> 6;
  const int t0 = half * 256;
  float* qk_p = smem;            // 288
  float* v_p = smem + 288;       // 288
  float* scr = smem + 576;       // 4096
  float* ep = smem + 4672;       // 256
  float* r16 = smem + 4928;      // 16
  float* bc = smem + 4944;       // 2

  if (tid < 256) {
    qk_p[(tid >> 4) * 18 + (tid & 15)] = qkT[tid * B + b];
    v_p[(tid >> 4) * 18 + (tid & 15)] = v_att[tid];
  }
  __syncthreads();

  {  // e-pass: 32 groups x 16 lanes, 8 rows each (2 in flight)
    const int l16 = tid & 15, g = tid >> 4;
    float qg[16], vg[16];
#pragma unroll
    for (int i = 0; i < 16; ++i) {
      qg[i] = qk_p[l16 * 18 + i];
      vg[i] = v_p[l16 * 18 + i];
    }
    const uint4* kB = reinterpret_cast<const uint4*>(keysB + (size_t)b * TIN * H);
#pragma unroll
    for (int p = 0; p < 4; ++p) {
      const int r1 = g + p * 64, r2 = r1 + 32;
      const uint4 a0 = kB[(size_t)(t0 + r1) * 32 + l16 * 2];
      const uint4 a1 = kB[(size_t)(t0 + r1) * 32 + l16 * 2 + 1];
      const uint4 b0 = kB[(size_t)(t0 + r2) * 32 + l16 * 2];
      const uint4 b1 = kB[(size_t)(t0 + r2) * 32 + l16 * 2 + 1];
      float ka[16], kb2[16];
      unpack8(a0, ka); unpack8(a1, ka + 8);
      unpack8(b0, kb2); unpack8(b1, kb2 + 8);
      float s1 = 0.f, s2 = 0.f;
#pragma unroll
      for (int i = 0; i < 16; ++i) {
        s1 += vg[i] * tanh_(ka[i] + qg[i]);
        s2 += vg[i] * tanh_(kb2[i] + qg[i]);
      }
#pragma unroll
      for (int m = 1; m < 16; m <<= 1) { s1 += __shfl_xor(s1, m, 16); s2 += __shfl_xor(s2, m, 16); }
      if (l16 == 0) { ep[r1] = s1; ep[r2] = s2; }
    }
  }
  __syncthreads();

  // partial softmax over 256 (4 waves)
  float ev = -1e30f, pv = 0.f;
  if (tid < 256) {
    ev = ep[tid];
    float mx = ev;
#pragma unroll
    for (int m = 1; m < 64; m <<= 1) mx = fmaxf(mx, __shfl_xor(mx, m));
    if (lane == 0) r16[wv] = mx;
  }
  __syncthreads();
  if (tid == 0)
    bc[0] = fmaxf(fmaxf(r16[0], r16[1]), fmaxf(r16[2], r16[3]));
  __syncthreads();
  const float M = bc[0];
  if (tid < 256) {
    pv = __expf(ev - M);
    ep[tid] = pv;
    pvalsS[(size_t)b * TIN + t0 + tid] = pv;
    float s = pv;
#pragma unroll
    for (int m = 1; m < 64; m <<= 1) s += __shfl_xor(s, m);
    if (lane == 0) r16[wv] = s;
  }
  __syncthreads();
  if (tid == 0) {
    msS[half * 2 * B + b] = M;
    msS[(half * 2 + 1) * B + b] = r16[0] + r16[1] + r16[2] + r16[3];
  }

  {  // partial context (unnormalized)
    const int kq8 = tid & 31, ts = tid >> 5;
    float a[8] = {0.f, 0.f, 0.f, 0.f, 0.f, 0.f, 0.f, 0.f};
    const uint4* mB = reinterpret_cast<const uint4*>(memB + (size_t)b * TIN * H);
#pragma unroll 4
    for (int i = 0; i < 16; ++i) {
      const int tt = ts * 16 + i;
      const float p = ep[tt];
      float mv[8];
      unpack8(mB[(size_t)(t0 + tt) * 32 + kq8], mv);
#pragma unroll
      for (int j = 0; j < 8; ++j) a[j] += p * mv[j];
    }
    float4* s4 = reinterpret_cast<float4*>(scr + ts * 256 + kq8 * 8);
    s4[0] = make_float4(a[0], a[1], a[2], a[3]);
    s4[1] = make_float4(a[4], a[5], a[6], a[7]);
  }
  __syncthreads();
  if (tid < 256) {
    float s = 0.f;
#pragma unroll
    for (int ts2 = 0; ts2 < 16; ++ts2) s += scr[ts2 * 256 + tid];
    pctxS[(size_t)(half * 256 + tid) * B + b] = s;
  }
}

// ---------------------------------------------------------------------------
// 6-deep pipeline, 896 blocks x 512 threads (single scheduling round):
// attn_half(i-2) [0..255], attGRU<2>(i) [256..383], qW(i-1) [384..511],
// d0<2>(i-3) [512..639], d1<2>(i-4) [640..767], dense+alpha(i-5) [768..895].
__global__ __launch_bounds__(512, 8) void k_pipe(
    int i, const unsigned short* __restrict__ wgA,
    const unsigned short* __restrict__ wg0, const unsigned short* __restrict__ wg1,
    const unsigned short* __restrict__ wqB, const float* __restrict__ v_att,
    const float* __restrict__ b_att, const float* __restrict__ b_d0,
    const float* __restrict__ b_d1, const unsigned short* __restrict__ keysB,
    const unsigned short* __restrict__ memB, const float* __restrict__ preT,
    float* __restrict__ qr, float* __restrict__ qkr, float* __restrict__ hd0r,
    float* __restrict__ hd1r, float* __restrict__ res0r, float* __restrict__ res1r,
    float* __restrict__ pvals, float* __restrict__ pctx, float* __restrict__ ms,
    const float* __restrict__ Wo, const float* __restrict__ bo,
    float* __restrict__ dout, float* __restrict__ alpha) {
  __shared__ alignas(16) float smem[9216];
  const int blk = blockIdx.x;
  if (blk < 256) {                      // attn_half(t = i-2)
    const int t = i - 2;
    if (t >= 0 && t < RSTEPS) {
      const int sl = t & 3;
      attn_half_body(blk >> 1, blk & 1, qkr + (size_t)sl * (256 * B), v_att,
                     keysB, memB, pvals + (size_t)sl * B * TIN,
                     pctx + (size_t)sl * 2 * HB, ms + (size_t)sl * 4 * B, smem);
    }
  } else if (blk < 384) {               // attGRU(t = i), 4 j's per block
    const int t = i;
    if (t < RSTEPS)
      gru_body<2>(wgA, PP, 0, H, preT + (size_t)t * PP * B, nullptr, nullptr,
                  nullptr, qr + (size_t)((t + 3) & 3) * HB, b_att,
                  qr + (size_t)(t & 3) * HB, nullptr, nullptr, blk - 256, smem);
  } else if (blk < 512) {               // qW(t = i-1)
    const int t = i - 1;
    if (t >= 0 && t < RSTEPS) {
      const int sl = t & 3;
      qw_body(blk - 384, qr + (size_t)sl * HB, wqB,
              qkr + (size_t)sl * (256 * B), smem);
    }
  } else if (blk < 640) {               // d0(t = i-3), ctx from 2 partials
    const int t = i - 3;
    if (t >= 0 && t < RSTEPS) {
      const int sl = t & 3;
      gru_body<2>(wg0, H, H, H, qr + (size_t)sl * HB, nullptr,
                  pctx + (size_t)sl * 2 * HB, ms + (size_t)sl * 4 * B,
                  hd0r + (size_t)((t + 3) & 3) * HB, b_d0,
                  hd0r + (size_t)sl * HB, qr + (size_t)sl * HB,
                  res0r + (size_t)sl * HB, blk - 512, smem);
    }
  } else if (blk < 768) {               // d1(t = i-4), 4 j's per block
    const int t = i - 4;
    if (t >= 0 && t < RSTEPS) {
      const int sl = t & 3;
      gru_body<2>(wg1, H, 0, H, res0r + (size_t)sl * HB, nullptr, nullptr,
                  nullptr, hd1r + (size_t)((t + 3) & 3) * HB, b_d1,
                  hd1r + (size_t)sl * HB, res0r + (size_t)sl * HB,
                  res1r + (size_t)sl * HB, blk - 640, smem);
    }
  } else {                              // dense+alpha(t = i-5)
    const int t = i - 5;
    if (t >= 0 && t < RSTEPS) {
      const int sl = t & 3;
      dense_body(t, blk - 768, res1r + (size_t)sl * HB, Wo, bo, dout,
                 pvals + (size_t)sl * B * TIN, ms + (size_t)sl * 4 * B, alpha,
                 smem);
    }
  }
}

// ---------------------------------------------------------------------------
extern "C" void kernel_launch(void* const* d_in, const int* in_sizes, int n_in,
                              void* d_out, int out_size, void* d_ws,
                              size_t ws_size, hipStream_t stream) {
  const float* outs   = (const float*)d_in[0];
  const float* memory = (const float*)d_in[1];
  const float* Wp0    = (const float*)d_in[2];
  const float* bp0    = (const float*)d_in[3];
  const float* Wp1    = (const float*)d_in[4];
  const float* bp1    = (const float*)d_in[5];
  const float* Wx_att = (const float*)d_in[6];
  const float* Wh_att = (const float*)d_in[7];
  const float* b_att  = (const float*)d_in[8];
  const float* Wq     = (const float*)d_in[9];
  const float* Wm     = (const float*)d_in[10];
  const float* v_att  = (const float*)d_in[11];
  const float* Wx_d0  = (const float*)d_in[12];
  const float* Wh_d0  = (const float*)d_in[13];
  const float* b_d0   = (const float*)d_in[14];
  const float* Wx_d1  = (const float*)d_in[15];
  const float* Wh_d1  = (const float*)d_in[16];
  const float* b_d1   = (const float*)d_in[17];
  const float* Wo     = (const float*)d_in[18];
  const float* bo     = (const float*)d_in[19];
  float* dout = (float*)d_out;
  float* wsf  = (float*)d_ws;

  size_t off = 0;  // in floats
  unsigned short* keysB = (unsigned short*)(wsf + off); off += (size_t)TIN * B * H / 2;
  unsigned short* memB  = (unsigned short*)(wsf + off); off += (size_t)TIN * B * H / 2;
  unsigned short* wqB   = (unsigned short*)(wsf + off); off += (size_t)256 * 256 / 2;
  unsigned short* wgA   = (unsigned short*)(wsf + off); off += (size_t)384 * 1024 / 2;
  unsigned short* wg0   = (unsigned short*)(wsf + off); off += (size_t)768 * 1024 / 2;
  unsigned short* wg1   = (unsigned short*)(wsf + off); off += (size_t)512 * 1024 / 2;
  float* preT  = wsf + off; off += (size_t)RSTEPS * PP * B;
  float* qr    = wsf + off; off += (size_t)4 * HB;
  float* qkr   = wsf + off; off += (size_t)4 * 256 * B;
  float* hd0r  = wsf + off; off += (size_t)4 * HB;
  float* hd1r  = wsf + off; off += (size_t)4 * HB;
  float* res0r = wsf + off; off += (size_t)4 * HB;
  float* res1r = wsf + off; off += (size_t)4 * HB;
  float* pvals = wsf + off; off += (size_t)4 * B * TIN;
  float* pctx  = wsf + off; off += (size_t)4 * 2 * HB;
  float* ms    = wsf + off; off += (size_t)4 * 4 * B;

  // zero ring slots read at the pipeline head: state(-1) lives in slot 3
  hipMemsetAsync(qr + 3 * HB, 0, (size_t)HB * sizeof(float), stream);
  hipMemsetAsync(hd0r + 3 * HB, 0, (size_t)HB * sizeof(float), stream);
  hipMemsetAsync(hd1r + 3 * HB, 0, (size_t)HB * sizeof(float), stream);

  k_keys<<<(TIN * B) / 32, 256, 0, stream>>>(memory, Wm, keysB);
  k_memB<<<TIN * B, 256, 0, stream>>>(memory, memB);
  k_prenet<<<RSTEPS * B, 256, 0, stream>>>(outs, Wp0, bp0, Wp1, bp1, preT);
  k_packWq<<<256, 256, 0, stream>>>(Wq, wqB);
  k_packG<<<(128 * 768 + 255) / 256, 256, 0, stream>>>(Wx_att, wgA, 128, 0);
  k_packG<<<(256 * 768 + 255) / 256, 256, 0, stream>>>(Wh_att, wgA, 256, 128);
  k_packG<<<(512 * 768 + 255) / 256, 256, 0, stream>>>(Wx_d0, wg0, 512, 0);
  k_packG<<<(256 * 768 + 255) / 256, 256, 0, stream>>>(Wh_d0, wg0, 256, 512);
  k_packG<<<(256 * 768 + 255) / 256, 256, 0, stream>>>(Wx_d1, wg1, 256, 0);
  k_packG<<<(256 * 768 + 255) / 256, 256, 0, stream>>>(Wh_d1, wg1, 256, 256);

  float* alpha = dout + (size_t)1000 * B * D;

  for (int i = 0; i < RSTEPS + 5; ++i) {
    k_pipe<<<896, 512, 0, stream>>>(i, wgA, wg0, wg1, wqB, v_att, b_att,
                                    b_d0, b_d1, keysB, memB, preT, qr, qkr,
                                    hd0r, hd1r, res0r, res1r, pvals, pctx, ms,
                                    Wo, bo, dout, alpha);
  }
}

// Round 17
// 7395.194 us; speedup vs baseline: 1.2757x; 1.2757x over previous
//
#include <hip/hip_runtime.h>

namespace {
constexpr int B = 128;      // batch
constexpr int D = 80;       // mel dim
constexpr int H = 256;      // hidden
constexpr int PP = 128;     // prenet out
constexpr int TIN = 512;    // encoder steps
constexpr int RSTEPS = 200; // reduced steps
constexpr int RF = 5;       // reduction factor
constexpr int HB = H * B;   // ring slot stride
}

__device__ __forceinline__ float sigm(float x) { return 1.f / (1.f + __expf(-x)); }
__device__ __forceinline__ float tanh_(float x) { return 1.f - 2.f / (__expf(2.f * x) + 1.f); }
__device__ __forceinline__ unsigned short f2bf(float f) {  // RNE
  unsigned int u = __float_as_uint(f);
  u += 0x7fffu + ((u >> 16) & 1u);
  return (unsigned short)(u >> 16);
}
__device__ __forceinline__ void bf2x(unsigned int w, float& f0, float& f1) {
  f0 = __uint_as_float(w << 16);
  f1 = __uint_as_float(w & 0xffff0000u);
}
__device__ __forceinline__ void unpack8(uint4 w, float* f) {
  bf2x(w.x, f[0], f[1]); bf2x(w.y, f[2], f[3]);
  bf2x(w.z, f[4], f[5]); bf2x(w.w, f[6], f[7]);
}
__device__ __forceinline__ float dot8(uint4 w, float4 x0, float4 x1) {
  float f0, f1, a;
  bf2x(w.x, f0, f1); a  = f0 * x0.x + f1 * x0.y;
  bf2x(w.y, f0, f1); a += f0 * x0.z + f1 * x0.w;
  bf2x(w.z, f0, f1); a += f0 * x1.x + f1 * x1.y;
  bf2x(w.w, f0, f1); a += f0 * x1.z + f1 * x1.w;
  return a;
}

// ---------------------------------------------------------------------------
// R13-proven layout: contiguous 32-row reads, scattered bf16 stores.
__global__ __launch_bounds__(256) void k_keys(const float* __restrict__ mem,
                                              const float* __restrict__ Wm,
                                              unsigned short* __restrict__ keysB) {
  const int k = threadIdx.x;
  const int m0 = blockIdx.x * 32;
  const float* xb = mem + (size_t)m0 * H;
  float acc[32];
#pragma unroll
  for (int i = 0; i < 32; ++i) acc[i] = 0.f;
  for (int h = 0; h < H; h += 4) {
    const float w0 = Wm[(h + 0) * H + k];
    const float w1 = Wm[(h + 1) * H + k];
    const float w2 = Wm[(h + 2) * H + k];
    const float w3 = Wm[(h + 3) * H + k];
#pragma unroll
    for (int mi = 0; mi < 32; ++mi) {
      const float4 x = *reinterpret_cast<const float4*>(xb + (size_t)mi * H + h);
      acc[mi] += x.x * w0 + x.y * w1 + x.z * w2 + x.w * w3;
    }
  }
#pragma unroll
  for (int mi = 0; mi < 32; ++mi) {
    const int m = m0 + mi, t = m >> 7, bb = m & 127;
    keysB[((size_t)bb * TIN + t) * H + k] = f2bf(acc[mi]);
  }
}

__global__ __launch_bounds__(256) void k_memB(const float* __restrict__ mem,
                                              unsigned short* __restrict__ memB) {
  const int m = blockIdx.x, t = m >> 7, bb = m & 127;
  memB[((size_t)bb * TIN + t) * H + threadIdx.x] = f2bf(mem[(size_t)m * H + threadIdx.x]);
}

__global__ __launch_bounds__(256) void k_packWq(const float* __restrict__ W,
                                                unsigned short* __restrict__ Wp) {
  const int idx = blockIdx.x * 256 + threadIdx.x;
  const int k = idx >> 8, c = idx & 255;
  Wp[(((size_t)(k >> 3) * 256) + c) * 8 + (k & 7)] = f2bf(W[idx]);
}

// pack GRU weight W[K][768] (cols z|r|c) -> row-interleaved bf16:
// dst[(rowOff+k)*1024 + (j>>1)*8 + (j&1)*4 + g]; slots 3,7 pad.
__global__ __launch_bounds__(256) void k_packG(const float* __restrict__ W,
                                               unsigned short* __restrict__ dst,
                                               int K, int rowOff) {
  const int idx = blockIdx.x * 256 + threadIdx.x;
  if (idx >= K * 768) return;
  const int k = idx / 768, c = idx - k * 768;
  const int g = c >> 8, j = c & 255;
  dst[((size_t)(rowOff + k) * 128 + (j >> 1)) * 8 + (j & 1) * 4 + g] = f2bf(W[idx]);
}

// Hoisted prenet -> preT[t][j][b] fp32
__global__ __launch_bounds__(256) void k_prenet(
    const float* __restrict__ outs, const float* __restrict__ Wp0,
    const float* __restrict__ bp0, const float* __restrict__ Wp1,
    const float* __restrict__ bp1, float* __restrict__ preT) {
  const int t = blockIdx.x >> 7, b = blockIdx.x & 127, tid = threadIdx.x;
  __shared__ float f[80];
  __shared__ float p0[256];
  __shared__ float s2[256];
  if (tid < 80)
    f[tid] = (t == 0) ? 0.f
                      : __builtin_nontemporal_load(
                            &outs[((size_t)(t * RF - 1) * B + b) * D + tid]);
  __syncthreads();
  {
    float a = bp0[tid];
#pragma unroll 8
    for (int k = 0; k < 80; ++k) a += f[k] * Wp0[k * 256 + tid];
    p0[tid] = fmaxf(a, 0.f);
  }
  __syncthreads();
  {
    const int c = tid & 127, kh = tid >> 7;
    float a = 0.f;
#pragma unroll 8
    for (int k = kh * 128; k < kh * 128 + 128; ++k) a += p0[k] * Wp1[k * 128 + c];
    s2[kh * 128 + c] = a;
  }
  __syncthreads();
  if (tid < 128)
    preT[((size_t)t * PP + tid) * B + b] = fmaxf(bp1[tid] + s2[tid] + s2[128 + tid], 0.f);
}

// ---------------------------------------------------------------------------
// 8-wave GRU body, NJP j-pairs per block. rel -> (grp = rel>>1, bh = rel&1).
// If pctx0 != nullptr, x2 reconstructed from attention partials via msp.
template <int NJP>
__device__ void gru_body(const unsigned short* __restrict__ wp, int K1, int K2,
                         int KH, const float* __restrict__ xT1,
                         const float* __restrict__ xT2,
                         const float* __restrict__ pctx0,
                         const float* __restrict__ msp,
                         const float* __restrict__ hT_old,
                         const float* __restrict__ b3, float* __restrict__ hT_new,
                         const float* __restrict__ resInT,
                         float* __restrict__ resOutT, int rel, float* smem) {
  const int tid = threadIdx.x;
  float* part = smem;                       // 8 * NJP*512
  float* red = smem + 8 * NJP * 512;        // NJP*512
  const int grp = rel >> 1, bh = rel & 1;
  const int lane = tid & 63, wv = tid >> 6;
  const int b = bh * 64 + lane;

  float c0 = 0.f, c1 = 0.f;
  if (pctx0) {
    const float m0 = msp[b], s0 = msp[B + b];
    const float m1 = msp[2 * B + b], s1 = msp[3 * B + b];
    const float M = fmaxf(m0, m1);
    const float e0 = __expf(m0 - M), e1 = __expf(m1 - M);
    const float inv = 1.f / (s0 * e0 + s1 * e1);
    c0 = e0 * inv; c1 = e1 * inv;
  }

  const uint4* wp4 = reinterpret_cast<const uint4*>(wp);
  const int K12 = K1 + K2, KT = K12 + KH;
  const int KS = KT >> 3;
  const int k0 = wv * KS, k1 = k0 + KS;

  float acc[NJP * 8];
#pragma unroll
  for (int i = 0; i < NJP * 8; ++i) acc[i] = 0.f;
  float f0, f1;

#define UPD(wq, xv, base, CS)                                                  \
  bf2x(wq.x, f0, f1); acc[base + 0] += f0 * xv; acc[base + 1] += f1 * xv;      \
  bf2x(wq.y, f0, f1); acc[base + CS] += f0 * xv;                               \
  bf2x(wq.z, f0, f1); acc[base + 4] += f0 * xv; acc[base + 5] += f1 * xv;      \
  bf2x(wq.w, f0, f1); acc[base + 4 + CS] += f0 * xv;

  const int e1i = (k1 < K1) ? k1 : K1;
#pragma unroll 2
  for (int k = k0; k < e1i; ++k) {
    const float x = xT1[k * B + b];
#pragma unroll
    for (int p = 0; p < NJP; ++p) {
      const uint4 w = wp4[(size_t)k * 128 + grp * NJP + p];
      UPD(w, x, p * 8, 2)
    }
  }
  const int s2i = (k0 > K1) ? k0 : K1, e2i = (k1 < K12) ? k1 : K12;
#pragma unroll 2
  for (int k = s2i; k < e2i; ++k) {
    const int kk = k - K1;
    const float x = pctx0 ? (c0 * pctx0[kk * B + b] + c1 * pctx0[(256 + kk) * B + b])
                          : xT2[kk * B + b];
#pragma unroll
    for (int p = 0; p < NJP; ++p) {
      const uint4 w = wp4[(size_t)k * 128 + grp * NJP + p];
      UPD(w, x, p * 8, 2)
    }
  }
  const int s3i = (k0 > K12) ? k0 : K12;
#pragma unroll 2
  for (int k = s3i; k < k1; ++k) {
    const float x = hT_old[(k - K12) * B + b];
#pragma unroll
    for (int p = 0; p < NJP; ++p) {
      const uint4 w = wp4[(size_t)k * 128 + grp * NJP + p];
      UPD(w, x, p * 8, 3)
    }
  }
#undef UPD

  float* pw = part + wv * (NJP * 512);
#pragma unroll
  for (int i = 0; i < NJP * 8; ++i) pw[i * 64 + lane] = acc[i];
  __syncthreads();
  for (int idx = tid; idx < NJP * 512; idx += 512) {
    float s = 0.f;
#pragma unroll
    for (int w = 0; w < 8; ++w) s += part[w * (NJP * 512) + idx];
    red[idx] = s;
  }
  __syncthreads();
  if (tid < NJP * 128) {
    const int jl = tid >> 6, ln = tid & 63;
    const int j = grp * (NJP * 2) + jl;
    const int bb = bh * 64 + ln;
    const float az = red[(jl * 4 + 0) * 64 + ln];
    const float ar = red[(jl * 4 + 1) * 64 + ln];
    const float acx = red[(jl * 4 + 2) * 64 + ln];
    const float ach = red[(jl * 4 + 3) * 64 + ln];
    const float z = sigm(az + b3[j]);
    const float r = sigm(ar + b3[H + j]);
    const float c = tanh_(acx + r * ach + b3[2 * H + j]);
    const float hold = hT_old[j * B + bb];
    const float hn = (1.f - z) * hold + z * c;
    hT_new[j * B + bb] = hn;
    if (resOutT) resOutT[j * B + bb] = resInT[j * B + bb] + hn;
  }
}

// dense (512 threads) + alpha finalize for step s, batch row b
__device__ void dense_body(int s, int b, const float* __restrict__ res1T,
                           const float* __restrict__ Wo,
                           const float* __restrict__ bo, float* __restrict__ dout,
                           const float* __restrict__ pvalsS,
                           const float* __restrict__ msS,
                           float* __restrict__ alpha, float* smem) {
  const int tid = threadIdx.x;
  float* red = smem;             // 256
  float* part = smem + 256;      // 512
  if (tid < 256) red[tid] = res1T[tid * B + b];
  __syncthreads();
  {
    const int ks = tid >> 7, c = tid & 127;
    float a = 0.f;
    if (c < D) {
#pragma unroll 8
      for (int k = ks * 64; k < ks * 64 + 64; ++k) a += red[k] * Wo[k * D + c];
    }
    part[ks * 128 + c] = a;
  }
  __syncthreads();
  if (tid < D) {
    float dv = bo[tid];
#pragma unroll
    for (int ks = 0; ks < 4; ++ks) dv += part[ks * 128 + tid];
    const size_t base = (size_t)s * RF * (B * D) + (size_t)b * D + tid;
#pragma unroll
    for (int i = 0; i < RF; ++i)
      __builtin_nontemporal_store(dv, &dout[base + (size_t)i * (B * D)]);
  }
  const float m0 = msS[b], s0 = msS[B + b], m1 = msS[2 * B + b], s1 = msS[3 * B + b];
  const float M = fmaxf(m0, m1);
  const float f0 = __expf(m0 - M), f1 = __expf(m1 - M);
  const float inv = 1.f / (s0 * f0 + s1 * f1);
  const float cc = (tid < 256) ? f0 * inv : f1 * inv;
  __builtin_nontemporal_store(pvalsS[(size_t)b * TIN + tid] * cc,
                              &alpha[((size_t)s * B + b) * TIN + tid]);
}

// attention half (512 threads): qW + e over 256 t's + partial softmax + pctx
__device__ void attn_half_body(int b, int half, const float* __restrict__ qT,
                               const unsigned short* __restrict__ wqB,
                               const float* __restrict__ v_att,
                               const unsigned short* __restrict__ keysB,
                               const unsigned short* __restrict__ memB,
                               float* __restrict__ pvalsS, float* __restrict__ pctxS,
                               float* __restrict__ msS, float* smem) {
  const int tid = threadIdx.x;
  const int lane = tid & 63, wv = tid >> 6;
  const int t0 = half * 256;
  float* hA = smem;              // 256
  float* qk_p = smem + 256;      // 288
  float* v_p = smem + 544;       // 288
  float* scr = smem + 832;       // 4096
  float* ep = smem + 4928;       // 256
  float* r16 = smem + 5184;      // 16
  float* bc = smem + 5200;       // 2

  if (tid < 256) {
    hA[tid] = qT[tid * B + b];
    v_p[(tid >> 4) * 18 + (tid & 15)] = v_att[tid];
  }
  __syncthreads();
  const float4* hA4 = reinterpret_cast<const float4*>(hA);
  const uint4* wQ = reinterpret_cast<const uint4*>(wqB);

  {  // qW: 2-way split-K, 256 cols
    const int c = tid & 255, ks = tid >> 8;
    float a = 0.f;
#pragma unroll
    for (int q = 0; q < 16; ++q) {
      const int kg = ks * 16 + q;
      a += dot8(wQ[(size_t)kg * 256 + c], hA4[kg * 2], hA4[kg * 2 + 1]);
    }
    scr[ks * 256 + c] = a;
  }
  __syncthreads();
  if (tid < 256)
    qk_p[(tid >> 4) * 18 + (tid & 15)] = scr[tid] + scr[256 + tid];
  __syncthreads();

  {  // e-pass: 32 groups x 16 lanes, 8 rows each (2 in flight)
    const int l16 = tid & 15, g = tid >> 4;
    float qg[16], vg[16];
#pragma unroll
    for (int i = 0; i < 16; ++i) {
      qg[i] = qk_p[l16 * 18 + i];
      vg[i] = v_p[l16 * 18 + i];
    }
    const uint4* kB = reinterpret_cast<const uint4*>(keysB + (size_t)b * TIN * H);
#pragma unroll
    for (int p = 0; p < 4; ++p) {
      const int r1 = g + p * 64, r2 = r1 + 32;
      const uint4 a0 = kB[(size_t)(t0 + r1) * 32 + l16 * 2];
      const uint4 a1 = kB[(size_t)(t0 + r1) * 32 + l16 * 2 + 1];
      const uint4 b0 = kB[(size_t)(t0 + r2) * 32 + l16 * 2];
      const uint4 b1 = kB[(size_t)(t0 + r2) * 32 + l16 * 2 + 1];
      float ka[16], kb2[16];
      unpack8(a0, ka); unpack8(a1, ka + 8);
      unpack8(b0, kb2); unpack8(b1, kb2 + 8);
      float s1 = 0.f, s2 = 0.f;
#pragma unroll
      for (int i = 0; i < 16; ++i) {
        s1 += vg[i] * tanh_(ka[i] + qg[i]);
        s2 += vg[i] * tanh_(kb2[i] + qg[i]);
      }
#pragma unroll
      for (int m = 1; m < 16; m <<= 1) { s1 += __shfl_xor(s1, m, 16); s2 += __shfl_xor(s2, m, 16); }
      if (l16 == 0) { ep[r1] = s1; ep[r2] = s2; }
    }
  }
  __syncthreads();

  // partial softmax over 256 (4 waves)
  float ev = -1e30f, pv = 0.f;
  if (tid < 256) {
    ev = ep[tid];
    float mx = ev;
#pragma unroll
    for (int m = 1; m < 64; m <<= 1) mx = fmaxf(mx, __shfl_xor(mx, m));
    if (lane == 0) r16[wv] = mx;
  }
  __syncthreads();
  if (tid == 0)
    bc[0] = fmaxf(fmaxf(r16[0], r16[1]), fmaxf(r16[2], r16[3]));
  __syncthreads();
  const float M = bc[0];
  if (tid < 256) {
    pv = __expf(ev - M);
    ep[tid] = pv;
    pvalsS[(size_t)b * TIN + t0 + tid] = pv;
    float s = pv;
#pragma unroll
    for (int m = 1; m < 64; m <<= 1) s += __shfl_xor(s, m);
    if (lane == 0) r16[wv] = s;
  }
  __syncthreads();
  if (tid == 0) {
    msS[half * 2 * B + b] = M;
    msS[(half * 2 + 1) * B + b] = r16[0] + r16[1] + r16[2] + r16[3];
  }

  {  // partial context (unnormalized)
    const int kq8 = tid & 31, ts = tid >> 5;
    float a[8] = {0.f, 0.f, 0.f, 0.f, 0.f, 0.f, 0.f, 0.f};
    const uint4* mB = reinterpret_cast<const uint4*>(memB + (size_t)b * TIN * H);
#pragma unroll 4
    for (int i = 0; i < 16; ++i) {
      const int tt = ts * 16 + i;
      const float p = ep[tt];
      float mv[8];
      unpack8(mB[(size_t)(t0 + tt) * 32 + kq8], mv);
#pragma unroll
      for (int j = 0; j < 8; ++j) a[j] += p * mv[j];
    }
    float4* s4 = reinterpret_cast<float4*>(scr + ts * 256 + kq8 * 8);
    s4[0] = make_float4(a[0], a[1], a[2], a[3]);
    s4[1] = make_float4(a[4], a[5], a[6], a[7]);
  }
  __syncthreads();
  if (tid < 256) {
    float s = 0.f;
#pragma unroll
    for (int ts2 = 0; ts2 < 16; ++ts2) s += scr[ts2 * 256 + tid];
    pctxS[(size_t)(half * 256 + tid) * B + b] = s;
  }
}

// ---------------------------------------------------------------------------
// 5-deep pipeline, 1024 blocks x 512 threads (single scheduling round):
// attn_half(i-1) [0..255], d0(i-2) [256..511], attGRU(i) [512..767],
// d1 NJP=2 (i-3) [768..895], dense+alpha(i-4) [896..1023]. Ring-4 buffers.
__global__ __launch_bounds__(512, 8) void k_pipe(
    int i, const unsigned short* __restrict__ wgA,
    const unsigned short* __restrict__ wg0, const unsigned short* __restrict__ wg1,
    const unsigned short* __restrict__ wqB, const float* __restrict__ v_att,
    const float* __restrict__ b_att, const float* __restrict__ b_d0,
    const float* __restrict__ b_d1, const unsigned short* __restrict__ keysB,
    const unsigned short* __restrict__ memB, const float* __restrict__ preT,
    float* __restrict__ qr, float* __restrict__ hd0r, float* __restrict__ hd1r,
    float* __restrict__ res0r, float* __restrict__ res1r,
    float* __restrict__ pvals, float* __restrict__ pctx, float* __restrict__ ms,
    const float* __restrict__ Wo, const float* __restrict__ bo,
    float* __restrict__ dout, float* __restrict__ alpha) {
  __shared__ alignas(16) float smem[9216];
  const int blk = blockIdx.x;
  if (blk < 256) {                      // attn_half(t = i-1)
    const int t = i - 1;
    if (t >= 0 && t < RSTEPS) {
      const int sl = t & 3;
      attn_half_body(blk >> 1, blk & 1, qr + (size_t)sl * HB, wqB, v_att, keysB,
                     memB, pvals + (size_t)sl * B * TIN,
                     pctx + (size_t)sl * 2 * HB, ms + (size_t)sl * 4 * B, smem);
    }
  } else if (blk < 512) {               // d0(t = i-2), ctx from partials
    const int t = i - 2;
    if (t >= 0 && t < RSTEPS) {
      const int sl = t & 3;
      gru_body<1>(wg0, H, H, H, qr + (size_t)sl * HB, nullptr,
                  pctx + (size_t)sl * 2 * HB, ms + (size_t)sl * 4 * B,
                  hd0r + (size_t)((t + 3) & 3) * HB, b_d0,
                  hd0r + (size_t)sl * HB, qr + (size_t)sl * HB,
                  res0r + (size_t)sl * HB, blk - 256, smem);
    }
  } else if (blk < 768) {               // attGRU(t = i)
    const int t = i;
    if (t < RSTEPS)
      gru_body<1>(wgA, PP, 0, H, preT + (size_t)t * PP * B, nullptr, nullptr,
                  nullptr, qr + (size_t)((t + 3) & 3) * HB, b_att,
                  qr + (size_t)(t & 3) * HB, nullptr, nullptr, blk - 512, smem);
  } else if (blk < 896) {               // d1(t = i-3), 4 j's per block
    const int t = i - 3;
    if (t >= 0 && t < RSTEPS) {
      const int sl = t & 3;
      gru_body<2>(wg1, H, 0, H, res0r + (size_t)sl * HB, nullptr, nullptr,
                  nullptr, hd1r + (size_t)((t + 3) & 3) * HB, b_d1,
                  hd1r + (size_t)sl * HB, res0r + (size_t)sl * HB,
                  res1r + (size_t)sl * HB, blk - 768, smem);
    }
  } else {                              // dense+alpha(t = i-4)
    const int t = i - 4;
    if (t >= 0 && t < RSTEPS) {
      const int sl = t & 3;
      dense_body(t, blk - 896, res1r + (size_t)sl * HB, Wo, bo, dout,
                 pvals + (size_t)sl * B * TIN, ms + (size_t)sl * 4 * B, alpha,
                 smem);
    }
  }
}

// ---------------------------------------------------------------------------
extern "C" void kernel_launch(void* const* d_in, const int* in_sizes, int n_in,
                              void* d_out, int out_size, void* d_ws,
                              size_t ws_size, hipStream_t stream) {
  const float* outs   = (const float*)d_in[0];
  const float* memory = (const float*)d_in[1];
  const float* Wp0    = (const float*)d_in[2];
  const float* bp0    = (const float*)d_in[3];
  const float* Wp1    = (const float*)d_in[4];
  const float* bp1    = (const float*)d_in[5];
  const float* Wx_att = (const float*)d_in[6];
  const float* Wh_att = (const float*)d_in[7];
  const float* b_att  = (const float*)d_in[8];
  const float* Wq     = (const float*)d_in[9];
  const float* Wm     = (const float*)d_in[10];
  const float* v_att  = (const float*)d_in[11];
  const float* Wx_d0  = (const float*)d_in[12];
  const float* Wh_d0  = (const float*)d_in[13];
  const float* b_d0   = (const float*)d_in[14];
  const float* Wx_d1  = (const float*)d_in[15];
  const float* Wh_d1  = (const float*)d_in[16];
  const float* b_d1   = (const float*)d_in[17];
  const float* Wo     = (const float*)d_in[18];
  const float* bo     = (const float*)d_in[19];
  float* dout = (float*)d_out;
  float* wsf  = (float*)d_ws;

  size_t off = 0;  // in floats
  unsigned short* keysB = (unsigned short*)(wsf + off); off += (size_t)TIN * B * H / 2;
  unsigned short* memB  = (unsigned short*)(wsf + off); off += (size_t)TIN * B * H / 2;
  unsigned short* wqB   = (unsigned short*)(wsf + off); off += (size_t)256 * 256 / 2;
  unsigned short* wgA   = (unsigned short*)(wsf + off); off += (size_t)384 * 1024 / 2;
  unsigned short* wg0   = (unsigned short*)(wsf + off); off += (size_t)768 * 1024 / 2;
  unsigned short* wg1   = (unsigned short*)(wsf + off); off += (size_t)512 * 1024 / 2;
  float* preT  = wsf + off; off += (size_t)RSTEPS * PP * B;
  float* qr    = wsf + off; off += (size_t)4 * HB;
  float* hd0r  = wsf + off; off += (size_t)4 * HB;
  float* hd1r  = wsf + off; off += (size_t)4 * HB;
  float* res0r = wsf + off; off += (size_t)4 * HB;
  float* res1r = wsf + off; off += (size_t)4 * HB;
  float* pvals = wsf + off; off += (size_t)4 * B * TIN;
  float* pctx  = wsf + off; off += (size_t)4 * 2 * HB;
  float* ms    = wsf + off; off += (size_t)4 * 4 * B;

  // zero ring slots read at the pipeline head: state(-1) lives in slot 3
  hipMemsetAsync(qr + 3 * HB, 0, (size_t)HB * sizeof(float), stream);
  hipMemsetAsync(hd0r + 3 * HB, 0, (size_t)HB * sizeof(float), stream);
  hipMemsetAsync(hd1r + 3 * HB, 0, (size_t)HB * sizeof(float), stream);

  k_keys<<<(TIN * B) / 32, 256, 0, stream>>>(memory, Wm, keysB);
  k_memB<<<TIN * B, 256, 0, stream>>>(memory, memB);
  k_prenet<<<RSTEPS * B, 256, 0, stream>>>(outs, Wp0, bp0, Wp1, bp1, preT);
  k_packWq<<<256, 256, 0, stream>>>(Wq, wqB);
  k_packG<<<(128 * 768 + 255) / 256, 256, 0, stream>>>(Wx_att, wgA, 128, 0);
  k_packG<<<(256 * 768 + 255) / 256, 256, 0, stream>>>(Wh_att, wgA, 256, 128);
  k_packG<<<(512 * 768 + 255) / 256, 256, 0, stream>>>(Wx_d0, wg0, 512, 0);
  k_packG<<<(256 * 768 + 255) / 256, 256, 0, stream>>>(Wh_d0, wg0, 256, 512);
  k_packG<<<(256 * 768 + 255) / 256, 256, 0, stream>>>(Wx_d1, wg1, 256, 0);
  k_packG<<<(256 * 768 + 255) / 256, 256, 0, stream>>>(Wh_d1, wg1, 256, 256);

  float* alpha = dout + (size_t)1000 * B * D;

  for (int i = 0; i < RSTEPS + 4; ++i) {
    k_pipe<<<1024, 512, 0, stream>>>(i, wgA, wg0, wg1, wqB, v_att, b_att,
                                     b_d0, b_d1, keysB, memB, preT, qr, hd0r,
                                     hd1r, res0r, res1r, pvals, pctx, ms, Wo,
                                     bo, dout, alpha);
  }
}